// Round 12
// baseline (249.489 us; speedup 1.0000x reference)
//
#include <hip/hip_runtime.h>
#include <math.h>

constexpr int kT = 12;
constexpr float kNeg = 0.2f;
constexpr float kEps = 1e-5f;
constexpr float kLog2e = 1.44269504088896f;

typedef __attribute__((ext_vector_type(8))) short bf16x8;
typedef __attribute__((ext_vector_type(4))) float f32x4;
typedef __attribute__((ext_vector_type(2))) float f32x2;

__device__ __forceinline__ short f2bf(float f) {
  union { float f; unsigned u; } v;
  v.f = f;
  return (short)((v.u + 0x7fffu + ((v.u >> 16) & 1u)) >> 16);
}
__device__ __forceinline__ unsigned pack2(float a, float b) {
  return (unsigned)(unsigned short)f2bf(a) | ((unsigned)(unsigned short)f2bf(b) << 16);
}

__device__ __forceinline__ float wave_reduce_sum(float v) {
#pragma unroll
  for (int o = 32; o > 0; o >>= 1) v += __shfl_xor(v, o);
  return v;
}

// quad_perm DPP helper (1 VALU op, no LDS pipe). CTRL: broadcast j = j*0x55,
// xor1 = 0xB1 ([1,0,3,2]), xor2 = 0x4E ([2,3,0,1]).
template <int CTRL>
__device__ __forceinline__ float qperm(float v) {
  int i = __float_as_int(v);
  return __int_as_float(__builtin_amdgcn_update_dpp(i, i, CTRL, 0xf, 0xf, false));
}

// ---------------------------------------------------------------------------
// prep: BN1 stats (wave per node, no barriers) + frag pre-packs (4 blocks:
// ffw1 (DFF-PERMUTED: GEMM1 C-layout == GEMM2 B-layout, kills the shfl
// repack in ff), ffw2, zelW1+W2, wal=W·al) + deg count — one launch.
// ---------------------------------------------------------------------------
__global__ void prep_kernel(const float* __restrict__ x, const float* __restrict__ g,
                            const float* __restrict__ b, float* __restrict__ scale,
                            float* __restrict__ shift, const float* __restrict__ fw1,
                            const float* __restrict__ fw2, const float* __restrict__ zW1,
                            const float* __restrict__ zW2, const float* __restrict__ al1,
                            const float* __restrict__ ar1, const float* __restrict__ al2,
                            const float* __restrict__ ar2, bf16x8* __restrict__ fw1f,
                            bf16x8* __restrict__ fw2f, bf16x8* __restrict__ zw1f,
                            bf16x8* __restrict__ zw2f, bf16x8* __restrict__ walf,
                            const int* __restrict__ dst1, const int* __restrict__ dst2,
                            int* __restrict__ deg1, int* __restrict__ deg2, int N, int E1,
                            int E2, int nBnBlk) {
  int blk = blockIdx.x;
  int lane = threadIdx.x & 63, wid = threadIdx.x >> 6;
  if (blk < nBnBlk) {
    int n = blk * 4 + wid;
    if (n < N) {
      const float* xr = x + (size_t)n * 768;
      float s = 0.f, s2 = 0.f;
#pragma unroll
      for (int c = 0; c < 3; c++) {
        float4 v = *(const float4*)&xr[c * 256 + lane * 4];
        s += v.x + v.y + v.z + v.w;
        s2 += v.x * v.x + v.y * v.y + v.z * v.z + v.w * v.w;
      }
      s = wave_reduce_sum(s);
      s2 = wave_reduce_sum(s2);
      if (lane == 0) {
        const float inv = 1.f / 768.f;
        float mean = s * inv;
        float var = s2 * inv - mean * mean;
        float sc = rsqrtf(var + kEps) * g[n];
        scale[n] = sc;
        shift[n] = b[n] - mean * sc;
      }
    }
    return;
  }
  blk -= nBnBlk;
  int m = lane & 15, q = lane >> 4;
  if (blk == 0) {
    // DFF permutation: A-row p=m of block mt holds true DFF row
    //   (mt>>1)*32 + (p>>2)*8 + (mt&1)*4 + (p&3)
    // so GEMM1 output acc[2kc+jj][r] at lane (m,q) = DFF kc*32+q*8+jj*4+r,
    // which is exactly GEMM2's B-fragment ordering (bf[j] <- DFF kc*32+q*8+j).
    for (int fi = wid; fi < 16; fi += 4) {
      int mt = fi >> 1, kc = fi & 1;
      int dff = (mt >> 1) * 32 + (m >> 2) * 8 + (mt & 1) * 4 + (m & 3);
      bf16x8 v;
#pragma unroll
      for (int j = 0; j < 8; j++) v[j] = f2bf(fw1[(kc * 32 + q * 8 + j) * 128 + dff]);
      fw1f[fi * 64 + lane] = v;
    }
    return;
  }
  if (blk == 1) {
    for (int fi = wid; fi < 16; fi += 4) {
      int mt2 = fi >> 2, kc2 = fi & 3;
      bf16x8 u;
#pragma unroll
      for (int j = 0; j < 8; j++) u[j] = f2bf(fw2[(kc2 * 32 + q * 8 + j) * 64 + mt2 * 16 + m]);
      fw2f[fi * 64 + lane] = u;
    }
    return;
  }
  if (blk == 2) {
    for (int fi = wid; fi < 8; fi += 4) {
      int mt = fi >> 1, kc = fi & 1;
      bf16x8 v, u;
#pragma unroll
      for (int j = 0; j < 8; j++) {
        int d = kc * 32 + q * 8 + j;
        v[j] = f2bf(zW1[d * 64 + mt * 16 + m]);
        u[j] = f2bf(zW2[d * 64 + mt * 16 + m]);
      }
      zw1f[fi * 64 + lane] = v;
      zw2f[fi * 64 + lane] = u;
    }
    return;
  }
  if (blk == 3) {
    // wal[f][d]: f=0..3 el1(h), 4..7 er1, 8..11 el2, 12..15 er2; pre-scaled log2e
    __shared__ float wal[16][64];
    for (int e0 = threadIdx.x; e0 < 1024; e0 += 256) {
      int f = e0 >> 6, d = e0 & 63;
      int h = f & 3;
      const float* av = (f < 4) ? al1 : (f < 8) ? ar1 : (f < 12) ? al2 : ar2;
      const float* W = (f < 8) ? zW1 : zW2;
      float s = 0.f;
#pragma unroll
      for (int e = 0; e < 16; e++) s += W[d * 64 + h * 16 + e] * av[h * 16 + e];
      wal[f][d] = s * kLog2e;
    }
    __syncthreads();
    if (wid == 0) {
#pragma unroll
      for (int kc = 0; kc < 2; kc++) {
        bf16x8 v;
#pragma unroll
        for (int j = 0; j < 8; j++) v[j] = f2bf(wal[m][kc * 32 + q * 8 + j]);
        walf[kc * 64 + lane] = v;
      }
    }
    return;
  }
  // deg blocks
  int i = (blk - 4) * 256 + threadIdx.x;
  if (i < E1) atomicAdd(&deg1[dst1[i]], 1);
  else if (i < E1 + E2) atomicAdd(&deg2[dst2[i - E1]], 1);
}

// ---------------------------------------------------------------------------
// alloc: CSR range allocation WITHOUT a scan. Segment order is irrelevant
// (disjoint ranges suffice) — wave-reduce deg, one atomicAdd per wave per
// rel reserves the range, wave-local exclusive scan distributes bases.
// ---------------------------------------------------------------------------
__global__ void alloc_kernel(const int* __restrict__ deg1, int* __restrict__ off1,
                             int* __restrict__ ctr1, const int* __restrict__ deg2,
                             int* __restrict__ off2, int* __restrict__ ctr2, int N) {
  int n = blockIdx.x * 256 + threadIdx.x;
  int lane = threadIdx.x & 63;
  int d1 = (n < N) ? deg1[n] : 0;
  int d2 = (n < N) ? deg2[n] : 0;
  int i1 = d1, i2 = d2;
#pragma unroll
  for (int o = 1; o < 64; o <<= 1) {
    int y1 = __shfl_up(i1, o), y2 = __shfl_up(i2, o);
    if (lane >= o) { i1 += y1; i2 += y2; }
  }
  int tot1 = __shfl(i1, 63), tot2 = __shfl(i2, 63);
  int base1 = 0, base2 = 0;
  if (lane == 0) {
    base1 = atomicAdd(ctr1, tot1);
    base2 = atomicAdd(ctr2, tot2);
  }
  base1 = __shfl(base1, 0);
  base2 = __shfl(base2, 0);
  if (n < N) {
    off1[n] = base1 + i1 - d1;
    off2[n] = base2 + i2 - d2;
  }
}

// ---------------------------------------------------------------------------
// fill + zel fused (disjoint block ranges; independent work overlaps).
// zel: MFMA z + MFMA el/er (wal trick), 2 tiles per wave.
// ---------------------------------------------------------------------------
__global__ __launch_bounds__(256, 4) void fillzel_kernel(
    // fill args
    const int* __restrict__ src1, const int* __restrict__ dst1, const int* __restrict__ off1,
    int* __restrict__ cur1, int* __restrict__ scsr1, const int* __restrict__ src2,
    const int* __restrict__ dst2, const int* __restrict__ off2, int* __restrict__ cur2,
    int* __restrict__ scsr2, int E1, int E2, int nZelBlk,
    // zel args
    const float* __restrict__ x, const float* __restrict__ scale,
    const float* __restrict__ shift, const bf16x8* __restrict__ zw1f,
    const bf16x8* __restrict__ zw2f, const bf16x8* __restrict__ walf,
    unsigned short* __restrict__ z1, unsigned short* __restrict__ z2,
    float* __restrict__ el1, float* __restrict__ er1, float* __restrict__ el2,
    float* __restrict__ er2, int NT) {
  if ((int)blockIdx.x >= nZelBlk) {
    int i = ((int)blockIdx.x - nZelBlk) * 256 + threadIdx.x;
    if (i < E1) {
      int d = dst1[i];
      int p = atomicAdd(&cur1[d], 1);
      scsr1[off1[d] + p] = src1[i] * kT;
    } else if (i < E1 + E2) {
      int k = i - E1;
      int d = dst2[k];
      int p = atomicAdd(&cur2[d], 1);
      scsr2[off2[d] + p] = src2[k] * kT;
    }
    return;
  }
  __shared__ bf16x8 sW1[8][64];
  __shared__ bf16x8 sW2[8][64];
  __shared__ bf16x8 sWE[2][64];
  int lane = threadIdx.x & 63, wid = threadIdx.x >> 6;
  int m = lane & 15, q = lane >> 4;
  for (int fi = wid; fi < 8; fi += 4) {
    sW1[fi][lane] = zw1f[fi * 64 + lane];
    sW2[fi][lane] = zw2f[fi * 64 + lane];
  }
  if (wid == 0) {
    sWE[0][lane] = walf[lane];
    sWE[1][lane] = walf[64 + lane];
  }
  __syncthreads();
  int ntile = (NT + 15) / 16;
  int grp = blockIdx.x * 4 + wid;  // 2 tiles per wave: 2*grp, 2*grp+1
  if (grp * 2 >= ntile) return;

  bf16x8 hf[2][2];
  float scv[2], shv[2];
  int rowv[2], rowcv[2];
#pragma unroll
  for (int tt = 0; tt < 2; tt++) {
    int tile = grp * 2 + tt;
    int row = tile * 16 + m;
    int rowc = (row < NT) ? row : NT - 1;
    rowv[tt] = row;
    rowcv[tt] = rowc;
    int n = rowc / kT;
    scv[tt] = scale[n];
    shv[tt] = shift[n];
  }
#pragma unroll
  for (int tt = 0; tt < 2; tt++) {
    float sc = scv[tt], sh = shv[tt];
    int rowc = rowcv[tt];
#pragma unroll
    for (int kc = 0; kc < 2; kc++) {
      float4 p0 = *(const float4*)&x[(size_t)rowc * 64 + kc * 32 + q * 8];
      float4 p1 = *(const float4*)&x[(size_t)rowc * 64 + kc * 32 + q * 8 + 4];
      hf[tt][kc][0] = f2bf(fmaf(p0.x, sc, sh));
      hf[tt][kc][1] = f2bf(fmaf(p0.y, sc, sh));
      hf[tt][kc][2] = f2bf(fmaf(p0.z, sc, sh));
      hf[tt][kc][3] = f2bf(fmaf(p0.w, sc, sh));
      hf[tt][kc][4] = f2bf(fmaf(p1.x, sc, sh));
      hf[tt][kc][5] = f2bf(fmaf(p1.y, sc, sh));
      hf[tt][kc][6] = f2bf(fmaf(p1.z, sc, sh));
      hf[tt][kc][7] = f2bf(fmaf(p1.w, sc, sh));
    }
  }
  f32x4 a1[2][4], a2[2][4], ae[2];
#pragma unroll
  for (int tt = 0; tt < 2; tt++) {
#pragma unroll
    for (int mt = 0; mt < 4; mt++) {
      a1[tt][mt] = (f32x4){0.f, 0.f, 0.f, 0.f};
      a2[tt][mt] = (f32x4){0.f, 0.f, 0.f, 0.f};
    }
    ae[tt] = (f32x4){0.f, 0.f, 0.f, 0.f};
  }
#pragma unroll
  for (int kc = 0; kc < 2; kc++) {
#pragma unroll
    for (int mt = 0; mt < 4; mt++) {
#pragma unroll
      for (int tt = 0; tt < 2; tt++) {
        a1[tt][mt] = __builtin_amdgcn_mfma_f32_16x16x32_bf16(sW1[mt * 2 + kc][lane],
                                                             hf[tt][kc], a1[tt][mt], 0, 0, 0);
        a2[tt][mt] = __builtin_amdgcn_mfma_f32_16x16x32_bf16(sW2[mt * 2 + kc][lane],
                                                             hf[tt][kc], a2[tt][mt], 0, 0, 0);
      }
    }
#pragma unroll
    for (int tt = 0; tt < 2; tt++)
      ae[tt] = __builtin_amdgcn_mfma_f32_16x16x32_bf16(sWE[kc][lane], hf[tt][kc], ae[tt], 0,
                                                       0, 0);
  }
#pragma unroll
  for (int tt = 0; tt < 2; tt++) {
    int row = rowv[tt];
    if (row < NT) {
      // el/er store: quad q selects array; C-layout f=4q+r, col=m=row
      float* edst = (q == 0) ? el1 : (q == 1) ? er1 : (q == 2) ? el2 : er2;
      *(float4*)&edst[(size_t)row * 4] =
          make_float4(ae[tt][0], ae[tt][1], ae[tt][2], ae[tt][3]);
#pragma unroll
      for (int mt = 0; mt < 4; mt++) {
        uint2 u1 = {pack2(a1[tt][mt][0], a1[tt][mt][1]), pack2(a1[tt][mt][2], a1[tt][mt][3])};
        uint2 u2 = {pack2(a2[tt][mt][0], a2[tt][mt][1]), pack2(a2[tt][mt][2], a2[tt][mt][3])};
        *(uint2*)&z1[(size_t)row * 64 + mt * 16 + 4 * q] = u1;
        *(uint2*)&z2[(size_t)row * 64 + mt * 16 + 4 * q] = u2;
      }
    }
  }
}

// ---------------------------------------------------------------------------
// aggff v6: sbl-hoist. The edge-id block (sbl) and er are IDENTICAL across
// the 3 t-passes — r11's structure reloaded them per pass, exposing 6 serial
// ~500cy scsr latencies per wave (2 rels x 3 passes) with only ~1800cy of
// covered work. gat_rel3 goes rel-outer/chunk-outer/pass-inner: ONE scsr
// load per chunk feeds all 3 passes (den/n01/n23 per-pass accumulators,
// statically indexed). 6 stalls -> 2. Arithmetic order per pass unchanged.
// ---------------------------------------------------------------------------
struct GBuf {
  uint2 z0, z1, z2, z3;
  float e;
};

__device__ __forceinline__ void pf_group(int sbl, int eb, int t, int zvoff,
                                         const float* __restrict__ elp,
                                         const unsigned short* __restrict__ zp, int qidx,
                                         GBuf& G) {
  int sg = __shfl(sbl, eb + qidx) + t;
  G.e = elp[(size_t)sg * 4];
  int s0 = __builtin_amdgcn_readlane(sbl, eb);
  int s1 = __builtin_amdgcn_readlane(sbl, eb + 1);
  int s2 = __builtin_amdgcn_readlane(sbl, eb + 2);
  int s3 = __builtin_amdgcn_readlane(sbl, eb + 3);
  G.z0 = *(const uint2*)(zp + (size_t)s0 * 64 + zvoff);
  G.z1 = *(const uint2*)(zp + (size_t)s1 * 64 + zvoff);
  G.z2 = *(const uint2*)(zp + (size_t)s2 * 64 + zvoff);
  G.z3 = *(const uint2*)(zp + (size_t)s3 * 64 + zvoff);
}

__device__ __forceinline__ void cg_group(const GBuf& G, float er_h, int rem, int qidx,
                                         float& den, f32x2& n01, f32x2& n23) {
  float ev = G.e + er_h;
  ev = fmaxf(ev, kNeg * ev);
  float w = exp2f(ev);
  w = (qidx < rem) ? w : 0.f;  // clamped-duplicate edges contribute 0
  den += w;
  float w0 = qperm<0x00>(w);
  float w1 = qperm<0x55>(w);
  float w2 = qperm<0xAA>(w);
  float w3 = qperm<0xFF>(w);
  f32x2 v;
  v = (f32x2){__uint_as_float(G.z0.x << 16), __uint_as_float(G.z0.x & 0xffff0000u)};
  n01 += v * w0;
  v = (f32x2){__uint_as_float(G.z0.y << 16), __uint_as_float(G.z0.y & 0xffff0000u)};
  n23 += v * w0;
  v = (f32x2){__uint_as_float(G.z1.x << 16), __uint_as_float(G.z1.x & 0xffff0000u)};
  n01 += v * w1;
  v = (f32x2){__uint_as_float(G.z1.y << 16), __uint_as_float(G.z1.y & 0xffff0000u)};
  n23 += v * w1;
  v = (f32x2){__uint_as_float(G.z2.x << 16), __uint_as_float(G.z2.x & 0xffff0000u)};
  n01 += v * w2;
  v = (f32x2){__uint_as_float(G.z2.y << 16), __uint_as_float(G.z2.y & 0xffff0000u)};
  n23 += v * w2;
  v = (f32x2){__uint_as_float(G.z3.x << 16), __uint_as_float(G.z3.x & 0xffff0000u)};
  n01 += v * w3;
  v = (f32x2){__uint_as_float(G.z3.y << 16), __uint_as_float(G.z3.y & 0xffff0000u)};
  n23 += v * w3;
}

// All 3 t-passes for one rel; sbl + er hoisted. o01/o23 accumulate the
// per-pass softmax-normalized output (indices compile-time via unroll).
__device__ __forceinline__ void gat_rel3(int b0, int b1, int tl, int zvoff0,
                                         const int* __restrict__ scsr,
                                         const float* __restrict__ elp,
                                         const float* __restrict__ erb,
                                         const unsigned short* __restrict__ zp, int lane,
                                         int qidx, f32x2* o01, f32x2* o23) {
  if (b1 <= b0) return;
  float den[3];
  f32x2 n01[3], n23[3];
  float erh[3];
#pragma unroll
  for (int p = 0; p < 3; p++) {
    den[p] = 0.f;
    n01[p] = (f32x2){0.f, 0.f};
    n23[p] = (f32x2){0.f, 0.f};
    erh[p] = erb[(size_t)p * 16];  // row stride 4 rows * 4 floats
  }
  for (int c0 = b0; c0 < b1; c0 += 64) {
    int cnt = b1 - c0;
    if (cnt > 64) cnt = 64;
    int idx = c0 + lane;
    int sbl = scsr[(idx < b1) ? idx : b1 - 1];  // ONE load, shared by 3 passes
#pragma unroll
    for (int p = 0; p < 3; p++) {
      int t = p * 4 + tl;
      int zvo = zvoff0 + p * 256;
      GBuf A, B, C, D;
      pf_group(sbl, 0, t, zvo, elp, zp, qidx, A);
      if (cnt > 4) pf_group(sbl, 4, t, zvo, elp, zp, qidx, B);
      if (cnt > 8) pf_group(sbl, 8, t, zvo, elp, zp, qidx, C);
      int g = 0;
      while (true) {
        if (g + 12 < cnt) pf_group(sbl, g + 12, t, zvo, elp, zp, qidx, D);
        cg_group(A, erh[p], cnt - g, qidx, den[p], n01[p], n23[p]);
        g += 4;
        if (g >= cnt) break;
        if (g + 12 < cnt) pf_group(sbl, g + 12, t, zvo, elp, zp, qidx, A);
        cg_group(B, erh[p], cnt - g, qidx, den[p], n01[p], n23[p]);
        g += 4;
        if (g >= cnt) break;
        if (g + 12 < cnt) pf_group(sbl, g + 12, t, zvo, elp, zp, qidx, B);
        cg_group(C, erh[p], cnt - g, qidx, den[p], n01[p], n23[p]);
        g += 4;
        if (g >= cnt) break;
        if (g + 12 < cnt) pf_group(sbl, g + 12, t, zvo, elp, zp, qidx, C);
        cg_group(D, erh[p], cnt - g, qidx, den[p], n01[p], n23[p]);
        g += 4;
        if (g >= cnt) break;
      }
    }
  }
#pragma unroll
  for (int p = 0; p < 3; p++) {
    float d = den[p];
    d += qperm<0xB1>(d);
    d += qperm<0x4E>(d);
    float inv = 1.f / d;
    o01[p] += n01[p] * inv;
    o23[p] += n23[p] * inv;
  }
}

__global__ __launch_bounds__(512, 4) void aggff_kernel(
    const float* __restrict__ x, const int* __restrict__ scsr1,
    const int* __restrict__ off1, const int* __restrict__ deg1,
    const float* __restrict__ el1, const float* __restrict__ er1,
    const unsigned short* __restrict__ z1, const int* __restrict__ scsr2,
    const int* __restrict__ off2, const int* __restrict__ deg2,
    const float* __restrict__ el2, const float* __restrict__ er2,
    const unsigned short* __restrict__ z2, const float* __restrict__ bng,
    const float* __restrict__ bnb, const bf16x8* __restrict__ w1f,
    const bf16x8* __restrict__ w2f, const float* __restrict__ b1,
    const float* __restrict__ b2, float* __restrict__ out, int N, int NT) {
  __shared__ bf16x8 sW1[16][64];
  __shared__ float sB1[128];
  __shared__ float sB2[64];
  __shared__ float x2s[96][68];  // padded: byte stride 272 = 17*16 (f4-aligned, <=2-way banks)
  __shared__ float nsc[8], nsh[8];
  int lane = threadIdx.x & 63, wid = threadIdx.x >> 6;  // wid 0..7
  int m = lane & 15, q = lane >> 4;
  {
    int fi0 = wid * 2;
#pragma unroll
    for (int k = 0; k < 2; k++) sW1[fi0 + k][lane] = w1f[(fi0 + k) * 64 + lane];
    if (threadIdx.x < 128) sB1[threadIdx.x] = b1[threadIdx.x];
    else if (threadIdx.x < 192) sB2[threadIdx.x - 128] = b2[threadIdx.x - 128];
  }

  // ---- Phase A: wave wid owns node n; sbl hoisted across the 3 t-passes ----
  int n = blockIdx.x * 8 + wid;
  int tl = lane >> 4, cg = lane & 15;
  int h = cg >> 2;
  int qidx = lane & 3;
  if (n < N) {
    int b0a = off1[n], b1a = b0a + deg1[n];
    int b0b = off2[n], b1b = b0b + deg2[n];
    int zvoff0 = tl * 64 + cg * 4;
    f32x2 o01[3], o23[3];
#pragma unroll
    for (int p = 0; p < 3; p++) {
      o01[p] = (f32x2){0.f, 0.f};
      o23[p] = (f32x2){0.f, 0.f};
    }
    const float* erb1 = er1 + ((size_t)(n * kT + tl) * 4 + h);
    const float* erb2 = er2 + ((size_t)(n * kT + tl) * 4 + h);
    gat_rel3(b0a, b1a, tl, zvoff0, scsr1, el1 + h, erb1, z1, lane, qidx, o01, o23);
    gat_rel3(b0b, b1b, tl, zvoff0, scsr2, el2 + h, erb2, z2, lane, qidx, o01, o23);
    float s1acc = 0.f, s2acc = 0.f;
#pragma unroll
    for (int p = 0; p < 3; p++) {
      int t = p * 4 + tl;
      int row = n * kT + t;
      size_t base = (size_t)row * 64 + cg * 4;
      float4 xr = *(const float4*)&x[base];
      float4 o;
      o.x = xr.x + o01[p].x;
      o.y = xr.y + o01[p].y;
      o.z = xr.z + o23[p].x;
      o.w = xr.w + o23[p].y;
      *(float4*)&x2s[wid * 12 + t][cg * 4] = o;
      s1acc += o.x + o.y + o.z + o.w;
      s2acc += o.x * o.x + o.y * o.y + o.z * o.z + o.w * o.w;
    }
    float s1 = wave_reduce_sum(s1acc);
    float s2 = wave_reduce_sum(s2acc);
    if (lane == 0) {
      const float inv = 1.f / 768.f;
      float mean = s1 * inv;
      float var = s2 * inv - mean * mean;
      float sc = rsqrtf(var + kEps) * bng[n];
      nsc[wid] = sc;
      nsh[wid] = bnb[n] - mean * sc;
    }
  } else if (lane == 0) {
    nsc[wid] = 0.f;
    nsh[wid] = 0.f;
  }
  __syncthreads();

  // ---- Phase B: ff on the block's 96 rows (6 tiles, waves 0..5).
  //      GEMM1: LDS W1. GEMM2: W2 frags from global, issued BEFORE each kc's
  //      GELU (8 erff >> load latency; table is L2-resident across blocks).
  if (wid >= 6) return;
  int lrow = wid * 16 + m;                 // block-local row 0..95
  int grow = blockIdx.x * 96 + lrow;       // global row
  float sc = nsc[lrow / kT], sh = nsh[lrow / kT];

  bf16x8 hf[2];
#pragma unroll
  for (int kc = 0; kc < 2; kc++) {
    const float4 p0 = *(const float4*)&x2s[lrow][kc * 32 + q * 8];
    const float4 p1 = *(const float4*)&x2s[lrow][kc * 32 + q * 8 + 4];
    hf[kc][0] = f2bf(fmaf(p0.x, sc, sh));
    hf[kc][1] = f2bf(fmaf(p0.y, sc, sh));
    hf[kc][2] = f2bf(fmaf(p0.z, sc, sh));
    hf[kc][3] = f2bf(fmaf(p0.w, sc, sh));
    hf[kc][4] = f2bf(fmaf(p1.x, sc, sh));
    hf[kc][5] = f2bf(fmaf(p1.y, sc, sh));
    hf[kc][6] = f2bf(fmaf(p1.z, sc, sh));
    hf[kc][7] = f2bf(fmaf(p1.w, sc, sh));
  }

  f32x4 acc[8];
#pragma unroll
  for (int mt = 0; mt < 8; mt++) acc[mt] = (f32x4){0.f, 0.f, 0.f, 0.f};
#pragma unroll
  for (int kc = 0; kc < 2; kc++)
#pragma unroll
    for (int mt = 0; mt < 8; mt++)
      acc[mt] = __builtin_amdgcn_mfma_f32_16x16x32_bf16(sW1[mt * 2 + kc][lane], hf[kc],
                                                        acc[mt], 0, 0, 0);

  f32x4 acc2[4];
#pragma unroll
  for (int mt = 0; mt < 4; mt++) acc2[mt] = (f32x4){0.f, 0.f, 0.f, 0.f};
#pragma unroll
  for (int kc = 0; kc < 4; kc++) {
    // issue W2 frag loads first — consumed only after the GELU block below
    bf16x8 w2c0 = w2f[(0 * 4 + kc) * 64 + lane];
    bf16x8 w2c1 = w2f[(1 * 4 + kc) * 64 + lane];
    bf16x8 w2c2 = w2f[(2 * 4 + kc) * 64 + lane];
    bf16x8 w2c3 = w2f[(3 * 4 + kc) * 64 + lane];
    // lane-local GELU + B-frag: acc[2kc+jj][r] holds DFF kc*32+q*8+jj*4+r
    float4 bb0 = *(const float4*)&sB1[kc * 32 + q * 8];
    float4 bb1 = *(const float4*)&sB1[kc * 32 + q * 8 + 4];
    bf16x8 bf;
    float u;
    u = acc[2 * kc][0] + bb0.x; bf[0] = f2bf(0.5f * u * (1.f + erff(u * 0.70710678118654752f)));
    u = acc[2 * kc][1] + bb0.y; bf[1] = f2bf(0.5f * u * (1.f + erff(u * 0.70710678118654752f)));
    u = acc[2 * kc][2] + bb0.z; bf[2] = f2bf(0.5f * u * (1.f + erff(u * 0.70710678118654752f)));
    u = acc[2 * kc][3] + bb0.w; bf[3] = f2bf(0.5f * u * (1.f + erff(u * 0.70710678118654752f)));
    u = acc[2 * kc + 1][0] + bb1.x; bf[4] = f2bf(0.5f * u * (1.f + erff(u * 0.70710678118654752f)));
    u = acc[2 * kc + 1][1] + bb1.y; bf[5] = f2bf(0.5f * u * (1.f + erff(u * 0.70710678118654752f)));
    u = acc[2 * kc + 1][2] + bb1.z; bf[6] = f2bf(0.5f * u * (1.f + erff(u * 0.70710678118654752f)));
    u = acc[2 * kc + 1][3] + bb1.w; bf[7] = f2bf(0.5f * u * (1.f + erff(u * 0.70710678118654752f)));
    acc2[0] = __builtin_amdgcn_mfma_f32_16x16x32_bf16(w2c0, bf, acc2[0], 0, 0, 0);
    acc2[1] = __builtin_amdgcn_mfma_f32_16x16x32_bf16(w2c1, bf, acc2[1], 0, 0, 0);
    acc2[2] = __builtin_amdgcn_mfma_f32_16x16x32_bf16(w2c2, bf, acc2[2], 0, 0, 0);
    acc2[3] = __builtin_amdgcn_mfma_f32_16x16x32_bf16(w2c3, bf, acc2[3], 0, 0, 0);
  }

  if (grow < NT) {
#pragma unroll
    for (int mt = 0; mt < 4; mt++) {
      size_t base = (size_t)grow * 64 + mt * 16 + 4 * q;
      float4 xr = *(const float4*)&x2s[lrow][mt * 16 + 4 * q];
      float4 bb = *(const float4*)&sB2[mt * 16 + 4 * q];
      float4 o;
      o.x = acc2[mt][0] + bb.x + xr.x;
      o.y = acc2[mt][1] + bb.y + xr.y;
      o.z = acc2[mt][2] + bb.z + xr.z;
      o.w = acc2[mt][3] + bb.w + xr.w;
      *(float4*)&out[base] = o;
    }
  }
}

extern "C" void kernel_launch(void* const* d_in, const int* in_sizes, int n_in,
                              void* d_out, int out_size, void* d_ws, size_t ws_size,
                              hipStream_t stream) {
  const float* x = (const float*)d_in[0];
  const int* src1 = (const int*)d_in[1];
  const int* dst1 = (const int*)d_in[2];
  const int* src2 = (const int*)d_in[3];
  const int* dst2 = (const int*)d_in[4];
  const float* W1 = (const float*)d_in[5];
  const float* al1 = (const float*)d_in[6];
  const float* ar1 = (const float*)d_in[7];
  const float* W2 = (const float*)d_in[8];
  const float* al2 = (const float*)d_in[9];
  const float* ar2 = (const float*)d_in[10];
  const float* g1 = (const float*)d_in[11];
  const float* b1 = (const float*)d_in[12];
  const float* g2 = (const float*)d_in[13];
  const float* b2 = (const float*)d_in[14];
  const float* fw1 = (const float*)d_in[15];
  const float* fb1 = (const float*)d_in[16];
  const float* fw2 = (const float*)d_in[17];
  const float* fb2 = (const float*)d_in[18];

  const int N = in_sizes[11];
  const int E1 = in_sizes[1];
  const int E2 = in_sizes[3];
  const int NT = N * kT;

  char* p = (char*)d_ws;
  auto alloc = [&](size_t bytes) -> char* {
    char* r = p;
    p += (bytes + 255) & ~(size_t)255;
    return r;
  };
  unsigned short* z1 = (unsigned short*)alloc((size_t)NT * 64 * 2);
  unsigned short* z2 = (unsigned short*)alloc((size_t)NT * 64 * 2);
  float* el1 = (float*)alloc((size_t)NT * 4 * 4);
  float* er1 = (float*)alloc((size_t)NT * 4 * 4);
  float* el2 = (float*)alloc((size_t)NT * 4 * 4);
  float* er2 = (float*)alloc((size_t)NT * 4 * 4);
  float* sc1 = (float*)alloc((size_t)N * 4);
  float* sh1 = (float*)alloc((size_t)N * 4);
  int* off1 = (int*)alloc((size_t)(N + 1) * 4);
  int* off2 = (int*)alloc((size_t)(N + 1) * 4);
  int* scsr1 = (int*)alloc((size_t)E1 * 4);
  int* scsr2 = (int*)alloc((size_t)E2 * 4);
  bf16x8* fw1f = (bf16x8*)alloc(16 * 64 * 16);
  bf16x8* fw2f = (bf16x8*)alloc(16 * 64 * 16);
  bf16x8* zw1f = (bf16x8*)alloc(8 * 64 * 16);
  bf16x8* zw2f = (bf16x8*)alloc(8 * 64 * 16);
  bf16x8* walf = (bf16x8*)alloc(2 * 64 * 16);
  char* zero_base = p;
  int* deg1 = (int*)alloc((size_t)N * 4);
  int* cur1 = (int*)alloc((size_t)N * 4);
  int* deg2 = (int*)alloc((size_t)N * 4);
  int* cur2 = (int*)alloc((size_t)N * 4);
  int* ctrs = (int*)alloc(2 * 4);
  size_t zero_bytes = (size_t)(p - zero_base);
  hipMemsetAsync(zero_base, 0, zero_bytes, stream);

  const int nBnBlk = (N + 3) / 4;
  const int degBlk = (E1 + E2 + 255) / 256;
  prep_kernel<<<nBnBlk + 4 + degBlk, 256, 0, stream>>>(
      x, g1, b1, sc1, sh1, fw1, fw2, W1, W2, al1, ar1, al2, ar2, fw1f, fw2f, zw1f, zw2f, walf,
      dst1, dst2, deg1, deg2, N, E1, E2, nBnBlk);
  alloc_kernel<<<(N + 255) / 256, 256, 0, stream>>>(deg1, off1, &ctrs[0], deg2, off2,
                                                    &ctrs[1], N);
  const int ntile = (NT + 15) / 16;
  const int nZelBlk = (ntile / 2 + 3) / 4;  // 2 tiles per wave, 4 waves/block
  fillzel_kernel<<<nZelBlk + degBlk, 256, 0, stream>>>(
      src1, dst1, off1, cur1, scsr1, src2, dst2, off2, cur2, scsr2, E1, E2, nZelBlk, x, sc1,
      sh1, zw1f, zw2f, walf, z1, z2, el1, er1, el2, er2, NT);
  aggff_kernel<<<(N + 7) / 8, 512, 0, stream>>>(x, scsr1, off1, deg1, el1, er1, z1, scsr2,
                                                off2, deg2, el2, er2, z2, g2, b2, fw1f, fw2f,
                                                fb1, fb2, (float*)d_out, N, NT);
}

// Round 13
// 224.561 us; speedup vs baseline: 1.1110x; 1.1110x over previous
//
#include <hip/hip_runtime.h>
#include <math.h>

constexpr int kT = 12;
constexpr float kNeg = 0.2f;
constexpr float kEps = 1e-5f;
constexpr float kLog2e = 1.44269504088896f;

typedef __attribute__((ext_vector_type(8))) short bf16x8;
typedef __attribute__((ext_vector_type(4))) float f32x4;
typedef __attribute__((ext_vector_type(2))) float f32x2;

__device__ __forceinline__ short f2bf(float f) {
  union { float f; unsigned u; } v;
  v.f = f;
  return (short)((v.u + 0x7fffu + ((v.u >> 16) & 1u)) >> 16);
}
__device__ __forceinline__ unsigned pack2(float a, float b) {
  return (unsigned)(unsigned short)f2bf(a) | ((unsigned)(unsigned short)f2bf(b) << 16);
}

__device__ __forceinline__ float wave_reduce_sum(float v) {
#pragma unroll
  for (int o = 32; o > 0; o >>= 1) v += __shfl_xor(v, o);
  return v;
}

// quad_perm DPP helper (1 VALU op, no LDS pipe). CTRL: broadcast j = j*0x55,
// xor1 = 0xB1 ([1,0,3,2]), xor2 = 0x4E ([2,3,0,1]).
template <int CTRL>
__device__ __forceinline__ float qperm(float v) {
  int i = __float_as_int(v);
  return __int_as_float(__builtin_amdgcn_update_dpp(i, i, CTRL, 0xf, 0xf, false));
}

// ---------------------------------------------------------------------------
// prep: BN1 stats (wave per node, no barriers) + frag pre-packs (4 blocks:
// ffw1 (DFF-PERMUTED: GEMM1 C-layout == GEMM2 B-layout, kills the shfl
// repack in ff), ffw2, zelW1+W2, wal=W·al) + deg count — one launch.
// ---------------------------------------------------------------------------
__global__ void prep_kernel(const float* __restrict__ x, const float* __restrict__ g,
                            const float* __restrict__ b, float* __restrict__ scale,
                            float* __restrict__ shift, const float* __restrict__ fw1,
                            const float* __restrict__ fw2, const float* __restrict__ zW1,
                            const float* __restrict__ zW2, const float* __restrict__ al1,
                            const float* __restrict__ ar1, const float* __restrict__ al2,
                            const float* __restrict__ ar2, bf16x8* __restrict__ fw1f,
                            bf16x8* __restrict__ fw2f, bf16x8* __restrict__ zw1f,
                            bf16x8* __restrict__ zw2f, bf16x8* __restrict__ walf,
                            const int* __restrict__ dst1, const int* __restrict__ dst2,
                            int* __restrict__ deg1, int* __restrict__ deg2, int N, int E1,
                            int E2, int nBnBlk) {
  int blk = blockIdx.x;
  int lane = threadIdx.x & 63, wid = threadIdx.x >> 6;
  if (blk < nBnBlk) {
    int n = blk * 4 + wid;
    if (n < N) {
      const float* xr = x + (size_t)n * 768;
      float s = 0.f, s2 = 0.f;
#pragma unroll
      for (int c = 0; c < 3; c++) {
        float4 v = *(const float4*)&xr[c * 256 + lane * 4];
        s += v.x + v.y + v.z + v.w;
        s2 += v.x * v.x + v.y * v.y + v.z * v.z + v.w * v.w;
      }
      s = wave_reduce_sum(s);
      s2 = wave_reduce_sum(s2);
      if (lane == 0) {
        const float inv = 1.f / 768.f;
        float mean = s * inv;
        float var = s2 * inv - mean * mean;
        float sc = rsqrtf(var + kEps) * g[n];
        scale[n] = sc;
        shift[n] = b[n] - mean * sc;
      }
    }
    return;
  }
  blk -= nBnBlk;
  int m = lane & 15, q = lane >> 4;
  if (blk == 0) {
    // DFF permutation: A-row p=m of block mt holds true DFF row
    //   (mt>>1)*32 + (p>>2)*8 + (mt&1)*4 + (p&3)
    // so GEMM1 output acc[2kc+jj][r] at lane (m,q) = DFF kc*32+q*8+jj*4+r,
    // which is exactly GEMM2's B-fragment ordering (bf[j] <- DFF kc*32+q*8+j).
    for (int fi = wid; fi < 16; fi += 4) {
      int mt = fi >> 1, kc = fi & 1;
      int dff = (mt >> 1) * 32 + (m >> 2) * 8 + (mt & 1) * 4 + (m & 3);
      bf16x8 v;
#pragma unroll
      for (int j = 0; j < 8; j++) v[j] = f2bf(fw1[(kc * 32 + q * 8 + j) * 128 + dff]);
      fw1f[fi * 64 + lane] = v;
    }
    return;
  }
  if (blk == 1) {
    for (int fi = wid; fi < 16; fi += 4) {
      int mt2 = fi >> 2, kc2 = fi & 3;
      bf16x8 u;
#pragma unroll
      for (int j = 0; j < 8; j++) u[j] = f2bf(fw2[(kc2 * 32 + q * 8 + j) * 64 + mt2 * 16 + m]);
      fw2f[fi * 64 + lane] = u;
    }
    return;
  }
  if (blk == 2) {
    for (int fi = wid; fi < 8; fi += 4) {
      int mt = fi >> 1, kc = fi & 1;
      bf16x8 v, u;
#pragma unroll
      for (int j = 0; j < 8; j++) {
        int d = kc * 32 + q * 8 + j;
        v[j] = f2bf(zW1[d * 64 + mt * 16 + m]);
        u[j] = f2bf(zW2[d * 64 + mt * 16 + m]);
      }
      zw1f[fi * 64 + lane] = v;
      zw2f[fi * 64 + lane] = u;
    }
    return;
  }
  if (blk == 3) {
    // wal[f][d]: f=0..3 el1(h), 4..7 er1, 8..11 el2, 12..15 er2; pre-scaled log2e
    __shared__ float wal[16][64];
    for (int e0 = threadIdx.x; e0 < 1024; e0 += 256) {
      int f = e0 >> 6, d = e0 & 63;
      int h = f & 3;
      const float* av = (f < 4) ? al1 : (f < 8) ? ar1 : (f < 12) ? al2 : ar2;
      const float* W = (f < 8) ? zW1 : zW2;
      float s = 0.f;
#pragma unroll
      for (int e = 0; e < 16; e++) s += W[d * 64 + h * 16 + e] * av[h * 16 + e];
      wal[f][d] = s * kLog2e;
    }
    __syncthreads();
    if (wid == 0) {
#pragma unroll
      for (int kc = 0; kc < 2; kc++) {
        bf16x8 v;
#pragma unroll
        for (int j = 0; j < 8; j++) v[j] = f2bf(wal[m][kc * 32 + q * 8 + j]);
        walf[kc * 64 + lane] = v;
      }
    }
    return;
  }
  // deg blocks
  int i = (blk - 4) * 256 + threadIdx.x;
  if (i < E1) atomicAdd(&deg1[dst1[i]], 1);
  else if (i < E1 + E2) atomicAdd(&deg2[dst2[i - E1]], 1);
}

// ---------------------------------------------------------------------------
// alloc: CSR range allocation WITHOUT a scan. Segment order is irrelevant
// (disjoint ranges suffice) — wave-reduce deg, one atomicAdd per wave per
// rel reserves the range, wave-local exclusive scan distributes bases.
// ---------------------------------------------------------------------------
__global__ void alloc_kernel(const int* __restrict__ deg1, int* __restrict__ off1,
                             int* __restrict__ ctr1, const int* __restrict__ deg2,
                             int* __restrict__ off2, int* __restrict__ ctr2, int N) {
  int n = blockIdx.x * 256 + threadIdx.x;
  int lane = threadIdx.x & 63;
  int d1 = (n < N) ? deg1[n] : 0;
  int d2 = (n < N) ? deg2[n] : 0;
  int i1 = d1, i2 = d2;
#pragma unroll
  for (int o = 1; o < 64; o <<= 1) {
    int y1 = __shfl_up(i1, o), y2 = __shfl_up(i2, o);
    if (lane >= o) { i1 += y1; i2 += y2; }
  }
  int tot1 = __shfl(i1, 63), tot2 = __shfl(i2, 63);
  int base1 = 0, base2 = 0;
  if (lane == 0) {
    base1 = atomicAdd(ctr1, tot1);
    base2 = atomicAdd(ctr2, tot2);
  }
  base1 = __shfl(base1, 0);
  base2 = __shfl(base2, 0);
  if (n < N) {
    off1[n] = base1 + i1 - d1;
    off2[n] = base2 + i2 - d2;
  }
}

// ---------------------------------------------------------------------------
// fill + zel fused (disjoint block ranges; independent work overlaps).
// zel: MFMA z + MFMA el/er (wal trick), 2 tiles per wave.
// ---------------------------------------------------------------------------
__global__ __launch_bounds__(256, 4) void fillzel_kernel(
    // fill args
    const int* __restrict__ src1, const int* __restrict__ dst1, const int* __restrict__ off1,
    int* __restrict__ cur1, int* __restrict__ scsr1, const int* __restrict__ src2,
    const int* __restrict__ dst2, const int* __restrict__ off2, int* __restrict__ cur2,
    int* __restrict__ scsr2, int E1, int E2, int nZelBlk,
    // zel args
    const float* __restrict__ x, const float* __restrict__ scale,
    const float* __restrict__ shift, const bf16x8* __restrict__ zw1f,
    const bf16x8* __restrict__ zw2f, const bf16x8* __restrict__ walf,
    unsigned short* __restrict__ z1, unsigned short* __restrict__ z2,
    float* __restrict__ el1, float* __restrict__ er1, float* __restrict__ el2,
    float* __restrict__ er2, int NT) {
  if ((int)blockIdx.x >= nZelBlk) {
    int i = ((int)blockIdx.x - nZelBlk) * 256 + threadIdx.x;
    if (i < E1) {
      int d = dst1[i];
      int p = atomicAdd(&cur1[d], 1);
      scsr1[off1[d] + p] = src1[i] * kT;
    } else if (i < E1 + E2) {
      int k = i - E1;
      int d = dst2[k];
      int p = atomicAdd(&cur2[d], 1);
      scsr2[off2[d] + p] = src2[k] * kT;
    }
    return;
  }
  __shared__ bf16x8 sW1[8][64];
  __shared__ bf16x8 sW2[8][64];
  __shared__ bf16x8 sWE[2][64];
  int lane = threadIdx.x & 63, wid = threadIdx.x >> 6;
  int m = lane & 15, q = lane >> 4;
  for (int fi = wid; fi < 8; fi += 4) {
    sW1[fi][lane] = zw1f[fi * 64 + lane];
    sW2[fi][lane] = zw2f[fi * 64 + lane];
  }
  if (wid == 0) {
    sWE[0][lane] = walf[lane];
    sWE[1][lane] = walf[64 + lane];
  }
  __syncthreads();
  int ntile = (NT + 15) / 16;
  int grp = blockIdx.x * 4 + wid;  // 2 tiles per wave: 2*grp, 2*grp+1
  if (grp * 2 >= ntile) return;

  bf16x8 hf[2][2];
  float scv[2], shv[2];
  int rowv[2], rowcv[2];
#pragma unroll
  for (int tt = 0; tt < 2; tt++) {
    int tile = grp * 2 + tt;
    int row = tile * 16 + m;
    int rowc = (row < NT) ? row : NT - 1;
    rowv[tt] = row;
    rowcv[tt] = rowc;
    int n = rowc / kT;
    scv[tt] = scale[n];
    shv[tt] = shift[n];
  }
#pragma unroll
  for (int tt = 0; tt < 2; tt++) {
    float sc = scv[tt], sh = shv[tt];
    int rowc = rowcv[tt];
#pragma unroll
    for (int kc = 0; kc < 2; kc++) {
      float4 p0 = *(const float4*)&x[(size_t)rowc * 64 + kc * 32 + q * 8];
      float4 p1 = *(const float4*)&x[(size_t)rowc * 64 + kc * 32 + q * 8 + 4];
      hf[tt][kc][0] = f2bf(fmaf(p0.x, sc, sh));
      hf[tt][kc][1] = f2bf(fmaf(p0.y, sc, sh));
      hf[tt][kc][2] = f2bf(fmaf(p0.z, sc, sh));
      hf[tt][kc][3] = f2bf(fmaf(p0.w, sc, sh));
      hf[tt][kc][4] = f2bf(fmaf(p1.x, sc, sh));
      hf[tt][kc][5] = f2bf(fmaf(p1.y, sc, sh));
      hf[tt][kc][6] = f2bf(fmaf(p1.z, sc, sh));
      hf[tt][kc][7] = f2bf(fmaf(p1.w, sc, sh));
    }
  }
  f32x4 a1[2][4], a2[2][4], ae[2];
#pragma unroll
  for (int tt = 0; tt < 2; tt++) {
#pragma unroll
    for (int mt = 0; mt < 4; mt++) {
      a1[tt][mt] = (f32x4){0.f, 0.f, 0.f, 0.f};
      a2[tt][mt] = (f32x4){0.f, 0.f, 0.f, 0.f};
    }
    ae[tt] = (f32x4){0.f, 0.f, 0.f, 0.f};
  }
#pragma unroll
  for (int kc = 0; kc < 2; kc++) {
#pragma unroll
    for (int mt = 0; mt < 4; mt++) {
#pragma unroll
      for (int tt = 0; tt < 2; tt++) {
        a1[tt][mt] = __builtin_amdgcn_mfma_f32_16x16x32_bf16(sW1[mt * 2 + kc][lane],
                                                             hf[tt][kc], a1[tt][mt], 0, 0, 0);
        a2[tt][mt] = __builtin_amdgcn_mfma_f32_16x16x32_bf16(sW2[mt * 2 + kc][lane],
                                                             hf[tt][kc], a2[tt][mt], 0, 0, 0);
      }
    }
#pragma unroll
    for (int tt = 0; tt < 2; tt++)
      ae[tt] = __builtin_amdgcn_mfma_f32_16x16x32_bf16(sWE[kc][lane], hf[tt][kc], ae[tt], 0,
                                                       0, 0);
  }
#pragma unroll
  for (int tt = 0; tt < 2; tt++) {
    int row = rowv[tt];
    if (row < NT) {
      // el/er store: quad q selects array; C-layout f=4q+r, col=m=row
      float* edst = (q == 0) ? el1 : (q == 1) ? er1 : (q == 2) ? el2 : er2;
      *(float4*)&edst[(size_t)row * 4] =
          make_float4(ae[tt][0], ae[tt][1], ae[tt][2], ae[tt][3]);
#pragma unroll
      for (int mt = 0; mt < 4; mt++) {
        uint2 u1 = {pack2(a1[tt][mt][0], a1[tt][mt][1]), pack2(a1[tt][mt][2], a1[tt][mt][3])};
        uint2 u2 = {pack2(a2[tt][mt][0], a2[tt][mt][1]), pack2(a2[tt][mt][2], a2[tt][mt][3])};
        *(uint2*)&z1[(size_t)row * 64 + mt * 16 + 4 * q] = u1;
        *(uint2*)&z2[(size_t)row * 64 + mt * 16 + 4 * q] = u2;
      }
    }
  }
}

// ---------------------------------------------------------------------------
// aggff v4 (r10 champion, reverted): 512-thread block = 8 waves = 8 nodes.
// W tables in LDS (r9: W-from-global puts 32 serial loads on Phase B's MFMA
// path). 8-node block amortizes the 32KB W stage over 2x nodes: LDS ~59KB ->
// 2 blocks/CU = 16 waves/CU for the latency-bound gather. Phase B: 6/8 waves.
// r12 lesson: passing local f32x2 arrays by pointer into gat_rel3 defeated
// SROA -> 77MB scratch spill; keep the per-pass gat_rel structure.
// ---------------------------------------------------------------------------
struct GBuf {
  uint2 z0, z1, z2, z3;
  float e;
};

__device__ __forceinline__ void pf_group(int sbl, int eb, int t, int zvoff,
                                         const float* __restrict__ elp,
                                         const unsigned short* __restrict__ zp, int qidx,
                                         GBuf& G) {
  int sg = __shfl(sbl, eb + qidx) + t;
  G.e = elp[(size_t)sg * 4];
  int s0 = __builtin_amdgcn_readlane(sbl, eb);
  int s1 = __builtin_amdgcn_readlane(sbl, eb + 1);
  int s2 = __builtin_amdgcn_readlane(sbl, eb + 2);
  int s3 = __builtin_amdgcn_readlane(sbl, eb + 3);
  G.z0 = *(const uint2*)(zp + (size_t)s0 * 64 + zvoff);
  G.z1 = *(const uint2*)(zp + (size_t)s1 * 64 + zvoff);
  G.z2 = *(const uint2*)(zp + (size_t)s2 * 64 + zvoff);
  G.z3 = *(const uint2*)(zp + (size_t)s3 * 64 + zvoff);
}

__device__ __forceinline__ void cg_group(const GBuf& G, float er_h, int rem, int qidx,
                                         float& den, f32x2& n01, f32x2& n23) {
  float ev = G.e + er_h;
  ev = fmaxf(ev, kNeg * ev);
  float w = exp2f(ev);
  w = (qidx < rem) ? w : 0.f;  // clamped-duplicate edges contribute 0
  den += w;
  float w0 = qperm<0x00>(w);
  float w1 = qperm<0x55>(w);
  float w2 = qperm<0xAA>(w);
  float w3 = qperm<0xFF>(w);
  f32x2 v;
  v = (f32x2){__uint_as_float(G.z0.x << 16), __uint_as_float(G.z0.x & 0xffff0000u)};
  n01 += v * w0;
  v = (f32x2){__uint_as_float(G.z0.y << 16), __uint_as_float(G.z0.y & 0xffff0000u)};
  n23 += v * w0;
  v = (f32x2){__uint_as_float(G.z1.x << 16), __uint_as_float(G.z1.x & 0xffff0000u)};
  n01 += v * w1;
  v = (f32x2){__uint_as_float(G.z1.y << 16), __uint_as_float(G.z1.y & 0xffff0000u)};
  n23 += v * w1;
  v = (f32x2){__uint_as_float(G.z2.x << 16), __uint_as_float(G.z2.x & 0xffff0000u)};
  n01 += v * w2;
  v = (f32x2){__uint_as_float(G.z2.y << 16), __uint_as_float(G.z2.y & 0xffff0000u)};
  n23 += v * w2;
  v = (f32x2){__uint_as_float(G.z3.x << 16), __uint_as_float(G.z3.x & 0xffff0000u)};
  n01 += v * w3;
  v = (f32x2){__uint_as_float(G.z3.y << 16), __uint_as_float(G.z3.y & 0xffff0000u)};
  n23 += v * w3;
}

__device__ __forceinline__ void gat_rel(int b0, int b1, int t, int zvoff,
                                        const int* __restrict__ scsr,
                                        const float* __restrict__ elp, float er_h,
                                        const unsigned short* __restrict__ zp, int lane,
                                        int qidx, f32x2& a01, f32x2& a23) {
  if (b1 <= b0) return;
  float den = 0.f;
  f32x2 n01 = {0.f, 0.f}, n23 = {0.f, 0.f};
  for (int c0 = b0; c0 < b1; c0 += 64) {
    int cnt = b1 - c0;
    if (cnt > 64) cnt = 64;
    int idx = c0 + lane;
    int sbl = scsr[(idx < b1) ? idx : b1 - 1];  // lanes >= cnt hold clamped last edge
    GBuf A, B, C, D;
    pf_group(sbl, 0, t, zvoff, elp, zp, qidx, A);
    if (cnt > 4) pf_group(sbl, 4, t, zvoff, elp, zp, qidx, B);
    if (cnt > 8) pf_group(sbl, 8, t, zvoff, elp, zp, qidx, C);
    int g = 0;
    while (true) {
      if (g + 12 < cnt) pf_group(sbl, g + 12, t, zvoff, elp, zp, qidx, D);
      cg_group(A, er_h, cnt - g, qidx, den, n01, n23);
      g += 4;
      if (g >= cnt) break;
      if (g + 12 < cnt) pf_group(sbl, g + 12, t, zvoff, elp, zp, qidx, A);
      cg_group(B, er_h, cnt - g, qidx, den, n01, n23);
      g += 4;
      if (g >= cnt) break;
      if (g + 12 < cnt) pf_group(sbl, g + 12, t, zvoff, elp, zp, qidx, B);
      cg_group(C, er_h, cnt - g, qidx, den, n01, n23);
      g += 4;
      if (g >= cnt) break;
      if (g + 12 < cnt) pf_group(sbl, g + 12, t, zvoff, elp, zp, qidx, C);
      cg_group(D, er_h, cnt - g, qidx, den, n01, n23);
      g += 4;
      if (g >= cnt) break;
    }
  }
  // quad-reduce den (lanes of a quad hold qidx-strided partials)
  den += qperm<0xB1>(den);
  den += qperm<0x4E>(den);
  float inv = 1.f / den;
  a01 += n01 * inv;
  a23 += n23 * inv;
}

__global__ __launch_bounds__(512, 4) void aggff_kernel(
    const float* __restrict__ x, const int* __restrict__ scsr1,
    const int* __restrict__ off1, const int* __restrict__ deg1,
    const float* __restrict__ el1, const float* __restrict__ er1,
    const unsigned short* __restrict__ z1, const int* __restrict__ scsr2,
    const int* __restrict__ off2, const int* __restrict__ deg2,
    const float* __restrict__ el2, const float* __restrict__ er2,
    const unsigned short* __restrict__ z2, const float* __restrict__ bng,
    const float* __restrict__ bnb, const bf16x8* __restrict__ w1f,
    const bf16x8* __restrict__ w2f, const float* __restrict__ b1,
    const float* __restrict__ b2, float* __restrict__ out, int N, int NT) {
  __shared__ bf16x8 sW1[16][64];
  __shared__ bf16x8 sW2[16][64];
  __shared__ float sB1[128];
  __shared__ float sB2[64];
  __shared__ float x2s[96][68];  // padded: byte stride 272 = 17*16 (f4-aligned, <=2-way banks)
  __shared__ float nsc[8], nsh[8];
  int lane = threadIdx.x & 63, wid = threadIdx.x >> 6;  // wid 0..7
  int m = lane & 15, q = lane >> 4;
  {
    int fi0 = wid * 2;
#pragma unroll
    for (int k = 0; k < 2; k++) {
      sW1[fi0 + k][lane] = w1f[(fi0 + k) * 64 + lane];
      sW2[fi0 + k][lane] = w2f[(fi0 + k) * 64 + lane];
    }
    if (threadIdx.x < 128) sB1[threadIdx.x] = b1[threadIdx.x];
    else if (threadIdx.x < 192) sB2[threadIdx.x - 128] = b2[threadIdx.x - 128];
  }

  // ---- Phase A: wave wid owns node n (all 12 t in 3 passes) ----
  int n = blockIdx.x * 8 + wid;
  int tl = lane >> 4, cg = lane & 15;
  int h = cg >> 2;
  int qidx = lane & 3;
  if (n < N) {
    int b0a = off1[n], b1a = b0a + deg1[n];
    int b0b = off2[n], b1b = b0b + deg2[n];
    float s1acc = 0.f, s2acc = 0.f;
#pragma unroll
    for (int p = 0; p < 3; p++) {
      int t = p * 4 + tl;
      int row = n * kT + t;
      int zvoff = t * 64 + cg * 4;
      f32x2 a01 = {0.f, 0.f}, a23 = {0.f, 0.f};
      gat_rel(b0a, b1a, t, zvoff, scsr1, el1 + h, er1[(size_t)row * 4 + h], z1, lane, qidx,
              a01, a23);
      gat_rel(b0b, b1b, t, zvoff, scsr2, el2 + h, er2[(size_t)row * 4 + h], z2, lane, qidx,
              a01, a23);
      size_t base = (size_t)row * 64 + cg * 4;
      float4 xr = *(const float4*)&x[base];
      float4 o;
      o.x = xr.x + a01.x;
      o.y = xr.y + a01.y;
      o.z = xr.z + a23.x;
      o.w = xr.w + a23.y;
      *(float4*)&x2s[wid * 12 + t][cg * 4] = o;
      s1acc += o.x + o.y + o.z + o.w;
      s2acc += o.x * o.x + o.y * o.y + o.z * o.z + o.w * o.w;
    }
    float s1 = wave_reduce_sum(s1acc);
    float s2 = wave_reduce_sum(s2acc);
    if (lane == 0) {
      const float inv = 1.f / 768.f;
      float mean = s1 * inv;
      float var = s2 * inv - mean * mean;
      float sc = rsqrtf(var + kEps) * bng[n];
      nsc[wid] = sc;
      nsh[wid] = bnb[n] - mean * sc;
    }
  } else if (lane == 0) {
    nsc[wid] = 0.f;
    nsh[wid] = 0.f;
  }
  __syncthreads();

  // ---- Phase B: ff on the block's 96 rows (6 tiles, waves 0..5), LDS W ----
  if (wid >= 6) return;
  int lrow = wid * 16 + m;                 // block-local row 0..95
  int grow = blockIdx.x * 96 + lrow;       // global row
  float sc = nsc[lrow / kT], sh = nsh[lrow / kT];

  bf16x8 hf[2];
#pragma unroll
  for (int kc = 0; kc < 2; kc++) {
    const float4 p0 = *(const float4*)&x2s[lrow][kc * 32 + q * 8];
    const float4 p1 = *(const float4*)&x2s[lrow][kc * 32 + q * 8 + 4];
    hf[kc][0] = f2bf(fmaf(p0.x, sc, sh));
    hf[kc][1] = f2bf(fmaf(p0.y, sc, sh));
    hf[kc][2] = f2bf(fmaf(p0.z, sc, sh));
    hf[kc][3] = f2bf(fmaf(p0.w, sc, sh));
    hf[kc][4] = f2bf(fmaf(p1.x, sc, sh));
    hf[kc][5] = f2bf(fmaf(p1.y, sc, sh));
    hf[kc][6] = f2bf(fmaf(p1.z, sc, sh));
    hf[kc][7] = f2bf(fmaf(p1.w, sc, sh));
  }

  f32x4 acc[8];
#pragma unroll
  for (int mt = 0; mt < 8; mt++) acc[mt] = (f32x4){0.f, 0.f, 0.f, 0.f};
#pragma unroll
  for (int kc = 0; kc < 2; kc++)
#pragma unroll
    for (int mt = 0; mt < 8; mt++)
      acc[mt] = __builtin_amdgcn_mfma_f32_16x16x32_bf16(sW1[mt * 2 + kc][lane], hf[kc],
                                                        acc[mt], 0, 0, 0);

  f32x4 acc2[4];
#pragma unroll
  for (int mt = 0; mt < 4; mt++) acc2[mt] = (f32x4){0.f, 0.f, 0.f, 0.f};
#pragma unroll
  for (int kc = 0; kc < 4; kc++) {
    // lane-local GELU + B-frag: acc[2kc+jj][r] holds DFF kc*32+q*8+jj*4+r
    float4 bb0 = *(const float4*)&sB1[kc * 32 + q * 8];
    float4 bb1 = *(const float4*)&sB1[kc * 32 + q * 8 + 4];
    bf16x8 bf;
    float u;
    u = acc[2 * kc][0] + bb0.x; bf[0] = f2bf(0.5f * u * (1.f + erff(u * 0.70710678118654752f)));
    u = acc[2 * kc][1] + bb0.y; bf[1] = f2bf(0.5f * u * (1.f + erff(u * 0.70710678118654752f)));
    u = acc[2 * kc][2] + bb0.z; bf[2] = f2bf(0.5f * u * (1.f + erff(u * 0.70710678118654752f)));
    u = acc[2 * kc][3] + bb0.w; bf[3] = f2bf(0.5f * u * (1.f + erff(u * 0.70710678118654752f)));
    u = acc[2 * kc + 1][0] + bb1.x; bf[4] = f2bf(0.5f * u * (1.f + erff(u * 0.70710678118654752f)));
    u = acc[2 * kc + 1][1] + bb1.y; bf[5] = f2bf(0.5f * u * (1.f + erff(u * 0.70710678118654752f)));
    u = acc[2 * kc + 1][2] + bb1.z; bf[6] = f2bf(0.5f * u * (1.f + erff(u * 0.70710678118654752f)));
    u = acc[2 * kc + 1][3] + bb1.w; bf[7] = f2bf(0.5f * u * (1.f + erff(u * 0.70710678118654752f)));
#pragma unroll
    for (int mt = 0; mt < 4; mt++)
      acc2[mt] = __builtin_amdgcn_mfma_f32_16x16x32_bf16(sW2[mt * 4 + kc][lane], bf, acc2[mt],
                                                         0, 0, 0);
  }

  if (grow < NT) {
#pragma unroll
    for (int mt = 0; mt < 4; mt++) {
      size_t base = (size_t)grow * 64 + mt * 16 + 4 * q;
      float4 xr = *(const float4*)&x2s[lrow][mt * 16 + 4 * q];
      float4 bb = *(const float4*)&sB2[mt * 16 + 4 * q];
      float4 o;
      o.x = acc2[mt][0] + bb.x + xr.x;
      o.y = acc2[mt][1] + bb.y + xr.y;
      o.z = acc2[mt][2] + bb.z + xr.z;
      o.w = acc2[mt][3] + bb.w + xr.w;
      *(float4*)&out[base] = o;
    }
  }
}

extern "C" void kernel_launch(void* const* d_in, const int* in_sizes, int n_in,
                              void* d_out, int out_size, void* d_ws, size_t ws_size,
                              hipStream_t stream) {
  const float* x = (const float*)d_in[0];
  const int* src1 = (const int*)d_in[1];
  const int* dst1 = (const int*)d_in[2];
  const int* src2 = (const int*)d_in[3];
  const int* dst2 = (const int*)d_in[4];
  const float* W1 = (const float*)d_in[5];
  const float* al1 = (const float*)d_in[6];
  const float* ar1 = (const float*)d_in[7];
  const float* W2 = (const float*)d_in[8];
  const float* al2 = (const float*)d_in[9];
  const float* ar2 = (const float*)d_in[10];
  const float* g1 = (const float*)d_in[11];
  const float* b1 = (const float*)d_in[12];
  const float* g2 = (const float*)d_in[13];
  const float* b2 = (const float*)d_in[14];
  const float* fw1 = (const float*)d_in[15];
  const float* fb1 = (const float*)d_in[16];
  const float* fw2 = (const float*)d_in[17];
  const float* fb2 = (const float*)d_in[18];

  const int N = in_sizes[11];
  const int E1 = in_sizes[1];
  const int E2 = in_sizes[3];
  const int NT = N * kT;

  char* p = (char*)d_ws;
  auto alloc = [&](size_t bytes) -> char* {
    char* r = p;
    p += (bytes + 255) & ~(size_t)255;
    return r;
  };
  unsigned short* z1 = (unsigned short*)alloc((size_t)NT * 64 * 2);
  unsigned short* z2 = (unsigned short*)alloc((size_t)NT * 64 * 2);
  float* el1 = (float*)alloc((size_t)NT * 4 * 4);
  float* er1 = (float*)alloc((size_t)NT * 4 * 4);
  float* el2 = (float*)alloc((size_t)NT * 4 * 4);
  float* er2 = (float*)alloc((size_t)NT * 4 * 4);
  float* sc1 = (float*)alloc((size_t)N * 4);
  float* sh1 = (float*)alloc((size_t)N * 4);
  int* off1 = (int*)alloc((size_t)(N + 1) * 4);
  int* off2 = (int*)alloc((size_t)(N + 1) * 4);
  int* scsr1 = (int*)alloc((size_t)E1 * 4);
  int* scsr2 = (int*)alloc((size_t)E2 * 4);
  bf16x8* fw1f = (bf16x8*)alloc(16 * 64 * 16);
  bf16x8* fw2f = (bf16x8*)alloc(16 * 64 * 16);
  bf16x8* zw1f = (bf16x8*)alloc(8 * 64 * 16);
  bf16x8* zw2f = (bf16x8*)alloc(8 * 64 * 16);
  bf16x8* walf = (bf16x8*)alloc(2 * 64 * 16);
  char* zero_base = p;
  int* deg1 = (int*)alloc((size_t)N * 4);
  int* cur1 = (int*)alloc((size_t)N * 4);
  int* deg2 = (int*)alloc((size_t)N * 4);
  int* cur2 = (int*)alloc((size_t)N * 4);
  int* ctrs = (int*)alloc(2 * 4);
  size_t zero_bytes = (size_t)(p - zero_base);
  hipMemsetAsync(zero_base, 0, zero_bytes, stream);

  const int nBnBlk = (N + 3) / 4;
  const int degBlk = (E1 + E2 + 255) / 256;
  prep_kernel<<<nBnBlk + 4 + degBlk, 256, 0, stream>>>(
      x, g1, b1, sc1, sh1, fw1, fw2, W1, W2, al1, ar1, al2, ar2, fw1f, fw2f, zw1f, zw2f, walf,
      dst1, dst2, deg1, deg2, N, E1, E2, nBnBlk);
  alloc_kernel<<<(N + 255) / 256, 256, 0, stream>>>(deg1, off1, &ctrs[0], deg2, off2,
                                                    &ctrs[1], N);
  const int ntile = (NT + 15) / 16;
  const int nZelBlk = (ntile / 2 + 3) / 4;  // 2 tiles per wave, 4 waves/block
  fillzel_kernel<<<nZelBlk + degBlk, 256, 0, stream>>>(
      src1, dst1, off1, cur1, scsr1, src2, dst2, off2, cur2, scsr2, E1, E2, nZelBlk, x, sc1,
      sh1, zw1f, zw2f, walf, z1, z2, el1, er1, el2, er2, NT);
  aggff_kernel<<<(N + 7) / 8, 512, 0, stream>>>(x, scsr1, off1, deg1, el1, er1, z1, scsr2,
                                                off2, deg2, el2, er2, z2, g2, b2, fw1f, fw2f,
                                                fb1, fb2, (float*)d_out, N, NT);
}